// Round 2
// baseline (806.644 us; speedup 1.0000x reference)
//
#include <hip/hip_runtime.h>

#define N_NODES  100000
#define N_EDGES  3200000
#define N_GRAPHS 64

// ---------------- degree / norm ----------------
__global__ void deg_count(const int* __restrict__ dst, int* __restrict__ deg) {
    int i = blockIdx.x * 256 + threadIdx.x;
    if (i < N_EDGES) atomicAdd(&deg[dst[i]], 1);
}

__global__ void dinv_kernel(const int* __restrict__ deg, float* __restrict__ dinv) {
    int i = blockIdx.x * 256 + threadIdx.x;
    if (i < N_NODES) dinv[i] = rsqrtf((float)(deg[i] + 1));  // +1 self loop
}

// ---------------- layer-1 matmul: hs = (x @ W1) * dinv, acc = hs ----------------
// x:[N,128] W:[128,16]  block = 256 thr = 16 rows x 16 cols, 6250 blocks
__global__ void mm1(const float* __restrict__ x, const float* __restrict__ W,
                    const float* __restrict__ dinv,
                    float* __restrict__ hs, float* __restrict__ acc) {
    __shared__ float ws[128 * 16];
    __shared__ float xs[16 * 129];   // +1 pad breaks 4-way bank conflict
    int t = threadIdx.x;
    int row0 = blockIdx.x * 16;
    for (int i = t; i < 2048; i += 256) ws[i] = W[i];
    for (int i = t; i < 2048; i += 256) {
        int r = i >> 7, c = i & 127;
        xs[r * 129 + c] = x[(row0 + r) * 128 + c];
    }
    __syncthreads();
    int row = t >> 4, col = t & 15;
    float a = 0.f;
#pragma unroll
    for (int k = 0; k < 128; k++) a += xs[row * 129 + k] * ws[k * 16 + col];
    float v = a * dinv[row0 + row];
    int o = (row0 + row) * 16 + col;
    hs[o] = v;
    acc[o] = v;
}

// ---------------- layer-2 matmul: hs2 = (h1 @ W2) * dinv, acc2 = hs2 ----------------
// h1:[N,16] W:[16,32]  block = 256 thr = 8 rows x 32 cols, 12500 blocks
__global__ void mm2(const float* __restrict__ h, const float* __restrict__ W,
                    const float* __restrict__ dinv,
                    float* __restrict__ hs, float* __restrict__ acc) {
    __shared__ float ws[16 * 32];
    __shared__ float xs[8 * 17];
    int t = threadIdx.x;
    int row0 = blockIdx.x * 8;
    // FIX (R1): W2 has 512 elements but block is 256 threads — previous
    // `if (t < 512) ws[t] = W[t];` left ws[256..511] uninitialized.
    for (int i = t; i < 512; i += 256) ws[i] = W[i];
    if (t < 128) {
        int r = t >> 4, c = t & 15;
        xs[r * 17 + c] = h[(row0 + r) * 16 + c];
    }
    __syncthreads();
    int row = t >> 5, col = t & 31;
    float a = 0.f;
#pragma unroll
    for (int k = 0; k < 16; k++) a += xs[row * 17 + k] * ws[k * 32 + col];
    float v = a * dinv[row0 + row];
    int o = (row0 + row) * 32 + col;
    hs[o] = v;
    acc[o] = v;
}

// ---------------- edge scatter: acc[dst] += hs[src] ----------------
__global__ void scatter16(const int* __restrict__ src, const int* __restrict__ dst,
                          const float* __restrict__ hs, float* __restrict__ acc) {
    long long i = blockIdx.x * 256LL + threadIdx.x;
    if (i >= (long long)N_EDGES * 16) return;
    int e = (int)(i >> 4), k = (int)(i & 15);
    atomicAdd(&acc[dst[e] * 16 + k], hs[src[e] * 16 + k]);
}

__global__ void scatter32(const int* __restrict__ src, const int* __restrict__ dst,
                          const float* __restrict__ hs, float* __restrict__ acc) {
    long long i = blockIdx.x * 256LL + threadIdx.x;
    if (i >= (long long)N_EDGES * 32) return;
    int e = (int)(i >> 5), k = (int)(i & 31);
    atomicAdd(&acc[dst[e] * 32 + k], hs[src[e] * 32 + k]);
}

// ---------------- finalize layer 1: acc = relu(dinv*acc + b) in place ----------------
__global__ void fin16(float* __restrict__ acc, const float* __restrict__ dinv,
                      const float* __restrict__ b) {
    int i = blockIdx.x * 256 + threadIdx.x;
    if (i >= N_NODES * 16) return;
    int v = i >> 4, k = i & 15;
    float r = dinv[v] * acc[i] + b[k];
    acc[i] = r > 0.f ? r : 0.f;
}

// ---------------- finalize layer 2 + mean-pool accumulation ----------------
// block = 256 thr handles 128 nodes (8 nodes x 32 feats per pass, 16 passes)
__global__ void fin32_pool(const float* __restrict__ acc, const float* __restrict__ dinv,
                           const float* __restrict__ b, const int* __restrict__ batch,
                           float* __restrict__ gsum, float* __restrict__ gcnt) {
    __shared__ float lsum[N_GRAPHS * 32];
    __shared__ float lcnt[N_GRAPHS];
    int t = threadIdx.x;
    for (int i = t; i < N_GRAPHS * 32; i += 256) lsum[i] = 0.f;
    if (t < N_GRAPHS) lcnt[t] = 0.f;
    __syncthreads();
    int base = blockIdx.x * 128;
    int k = t & 31, l = t >> 5;
    for (int i = 0; i < 16; i++) {
        int node = base + l + i * 8;
        if (node < N_NODES) {
            int g = batch[node];
            float r = dinv[node] * acc[node * 32 + k] + b[k];
            r = r > 0.f ? r : 0.f;
            atomicAdd(&lsum[g * 32 + k], r);
            if (k == 0) atomicAdd(&lcnt[g], 1.f);
        }
    }
    __syncthreads();
    // batch is sorted: this block only touched graphs [gmin, gmax]
    int gmin = batch[base];
    int last = base + 127; if (last > N_NODES - 1) last = N_NODES - 1;
    int gmax = batch[last];
    int ng = gmax - gmin + 1;
    for (int i = t; i < ng * 32; i += 256) {
        int g = gmin + (i >> 5);
        float v = lsum[g * 32 + (i & 31)];
        if (v != 0.f) atomicAdd(&gsum[g * 32 + (i & 31)], v);
    }
    for (int i = t; i < ng; i += 256) {
        float v = lcnt[gmin + i];
        if (v != 0.f) atomicAdd(&gcnt[gmin + i], v);
    }
}

// ---------------- head: mean -> fc1(relu) -> fc2, one block of 1024 ----------------
__global__ void head(const float* __restrict__ gsum, const float* __restrict__ gcnt,
                     const float* __restrict__ Wf1, const float* __restrict__ bf1,
                     const float* __restrict__ Wf2, const float* __restrict__ bf2,
                     float* __restrict__ out) {
    __shared__ float gm[64 * 32];
    __shared__ float f1[64 * 64];
    int t = threadIdx.x;  // 1024
    for (int i = t; i < 2048; i += 1024) {
        int g = i >> 5;
        float c = gcnt[g]; if (c < 1.f) c = 1.f;
        gm[i] = gsum[i] / c;
    }
    __syncthreads();
    for (int i = t; i < 4096; i += 1024) {
        int r = i >> 6, c = i & 63;
        float a = bf1[c];
#pragma unroll
        for (int j = 0; j < 32; j++) a += gm[r * 32 + j] * Wf1[j * 64 + c];
        f1[i] = a > 0.f ? a : 0.f;
    }
    __syncthreads();
    if (t < 512) {
        int r = t >> 3, c = t & 7;
        float a = bf2[c];
#pragma unroll
        for (int j = 0; j < 64; j++) a += f1[r * 64 + j] * Wf2[j * 8 + c];
        out[t] = a;
    }
}

extern "C" void kernel_launch(void* const* d_in, const int* in_sizes, int n_in,
                              void* d_out, int out_size, void* d_ws, size_t ws_size,
                              hipStream_t stream) {
    const float* x   = (const float*)d_in[0];
    const int*   ei  = (const int*)d_in[1];
    const int*   bat = (const int*)d_in[2];
    const float* W1  = (const float*)d_in[3];
    const float* b1  = (const float*)d_in[4];
    const float* W2  = (const float*)d_in[5];
    const float* b2  = (const float*)d_in[6];
    const float* Wf1 = (const float*)d_in[7];
    const float* bf1 = (const float*)d_in[8];
    const float* Wf2 = (const float*)d_in[9];
    const float* bf2 = (const float*)d_in[10];
    const int* src = ei;
    const int* dst = ei + N_EDGES;
    float* out = (float*)d_out;

    // workspace layout (128B-aligned offsets)
    char* ws = (char*)d_ws;
    int*   deg  = (int*)  (ws + 0);         //  400000 B
    float* dinv = (float*)(ws + 400384);    //  400000 B
    float* hs1  = (float*)(ws + 800768);    // 6400000 B
    float* acc1 = (float*)(ws + 7200768);   // 6400000 B
    float* hs2  = (float*)(ws + 13600768);  //12800000 B
    float* acc2 = (float*)(ws + 26400768);  //12800000 B
    float* gsum = (float*)(ws + 39200768);  //    8192 B
    float* gcnt = (float*)(ws + 39208960);  //     256 B

    hipMemsetAsync(deg, 0, N_NODES * sizeof(int), stream);
    hipMemsetAsync(gsum, 0, (N_GRAPHS * 32 + N_GRAPHS) * sizeof(float), stream);

    deg_count<<<(N_EDGES + 255) / 256, 256, 0, stream>>>(dst, deg);
    dinv_kernel<<<(N_NODES + 255) / 256, 256, 0, stream>>>(deg, dinv);

    // layer 1
    mm1<<<N_NODES / 16, 256, 0, stream>>>(x, W1, dinv, hs1, acc1);
    scatter16<<<(N_EDGES * 16 + 255) / 256, 256, 0, stream>>>(src, dst, hs1, acc1);
    fin16<<<(N_NODES * 16 + 255) / 256, 256, 0, stream>>>(acc1, dinv, b1);

    // layer 2
    mm2<<<N_NODES / 8, 256, 0, stream>>>(acc1, W2, dinv, hs2, acc2);
    scatter32<<<(N_EDGES * 32 + 255) / 256, 256, 0, stream>>>(src, dst, hs2, acc2);
    fin32_pool<<<(N_NODES + 127) / 128, 256, 0, stream>>>(acc2, dinv, b2, bat, gsum, gcnt);

    // head
    head<<<1, 1024, 0, stream>>>(gsum, gcnt, Wf1, bf1, Wf2, bf2, out);
}